// Round 3
// baseline (393.335 us; speedup 1.0000x reference)
//
#include <hip/hip_runtime.h>

// Problem constants (fixed by the reference's setup_inputs)
#define NB 2          // batch
#define NN 262144     // events per batch (2^18)
#define ND 10         // temporal bins (base)
#define NR 11         // warp references (base + 1)
#define HH 256
#define WW 256
#define HWSZ 65536
#define SROWS 4       // rows per y-strip
#define NSTRIP 64     // 256 / SROWS
#define PLANE (SROWS * WW)        // 1024 floats per (pol, e/t) plane
#define NRH0 6                    // half 0: r = 0..5
#define NRH1 5                    // half 1: r = 6..10
#define NBIN0 (NB * NRH0 * NSTRIP)   // 768
#define NBIN1 (NB * NRH1 * NSTRIP)   // 640
#define FILL_E 2048               // events per fill block
#define EPSF 1e-9f

// ws layout (23.09 MB -- matches the 23.07 MB proven-good ceiling):
//   float4 rec[NB*NN]   : (ax, ay, dx, dy)  warp at ref r = (ax+r*dx, ay+r*dy)
//   float  tsq[NB*NN]   : ts with sign bit = polarity (ts >= 0 always)
//   uint   bins[NB*NN*6]: per-(b, r-local, strip) index lists (reused per half)
//   uint   counts[1408] : [b][r][strip] exact pair counts
//   float  accum[64]    : (sumsq, inside) per (b,r)
//   uint   starts0/cursors0/starts1/cursors1 : bin offsets (+sentinel) per half
//
// R2 lesson (counters): ballot-queue scan = 292 us at VALUBusy 26%, VGPR 16 --
// a serial scalar chain doing 184M byte-tests for 6.3M hits (3.4% yield).
// Fix: classify each (event,r) ONCE, bin indices by (b,r,strip) with exact
// counts + LDS-staged reservation, then scan streams its bin DENSE (no filter,
// no ballots). Straddle into strip s+1 via flag bit; block s reads bin[s-1]
// flagged entries. Bins buffer reused across two r-halves to hold ws at 23 MB.

__device__ __forceinline__ unsigned strip_of(float ax, float ay, float dx, float dy, float rf)
{
    // returns 0 if no corner can land; else 0x80 | straddle<<6 | strip
    float wx = fmaf(rf, dx, ax);
    float wy = fmaf(rf, dy, ay);
    int xi = (int)floorf(wx);
    int yi = (int)floorf(wy);
    if (xi + 1 < 0 || xi >= WW || yi + 1 < 0 || yi >= HH) return 0u;
    int rr = yi < 0 ? 0 : yi;
    unsigned s = (unsigned)(rr >> 2);                 // SROWS = 4
    unsigned str = (yi >= 0 && yi + 1 < HH && ((yi & 3) == 3)) ? 0x40u : 0u;
    return 0x80u | str | s;
}

__global__ __launch_bounds__(1024) void cm_prep(
    const float* __restrict__ events,
    const float* __restrict__ flow,
    float4* __restrict__ rec,
    float* __restrict__ tsq,
    unsigned* __restrict__ counts)
{
    __shared__ unsigned hist[NR * NSTRIP];            // 704 counters, 2.8 KB
    for (int i = threadIdx.x; i < NR * NSTRIP; i += 1024) hist[i] = 0u;
    __syncthreads();

    int gid = blockIdx.x * 1024 + threadIdx.x;        // grid covers NB*NN exactly
    int b = gid >> 18;

    const float* e = events + (size_t)gid * 5;
    float x  = e[0];
    float y  = e[1];
    float t  = e[2];
    float ts = e[3];
    float p  = e[4];

    int zi = (int)floorf(t);
    zi = zi < 0 ? 0 : (zi > ND - 1 ? ND - 1 : zi);
    int x0 = (int)floorf(x);
    x0 = x0 < 0 ? 0 : (x0 > WW - 2 ? WW - 2 : x0);
    int y0 = (int)floorf(y);
    y0 = y0 < 0 ? 0 : (y0 > HH - 2 ? HH - 2 : y0);
    float fx = fminf(fmaxf(x - (float)x0, 0.0f), 1.0f);
    float fy = fminf(fmaxf(y - (float)y0, 0.0f), 1.0f);

    const float2* f2 = (const float2*)flow + ((size_t)b * ND + zi) * HWSZ;
    float2 f00 = f2[y0 * WW + x0];
    float2 f01 = f2[y0 * WW + x0 + 1];
    float2 f10 = f2[(y0 + 1) * WW + x0];
    float2 f11 = f2[(y0 + 1) * WW + x0 + 1];
    float w00 = (1.0f - fx) * (1.0f - fy);
    float w01 = fx * (1.0f - fy);
    float w10 = (1.0f - fx) * fy;
    float w11 = fx * fy;
    float flx = w00 * f00.x + w01 * f01.x + w10 * f10.x + w11 * f11.x;
    float fly = w00 * f00.y + w01 * f01.y + w10 * f10.y + w11 * f11.y;

    float ax = fmaf(-t, flx, x);
    float ay = fmaf(-t, fly, y);

    rec[gid] = make_float4(ax, ay, flx, fly);
    int pi = (p != 0.0f) ? 1 : 0;
    tsq[gid] = __int_as_float(__float_as_int(ts) | (pi << 31));   // ts >= 0

    #pragma unroll
    for (int r = 0; r < NR; ++r) {
        unsigned sb = strip_of(ax, ay, flx, fly, (float)r);
        if (sb & 0x80u) atomicAdd(&hist[r * NSTRIP + (int)(sb & 63u)], 1u);
    }
    __syncthreads();
    for (int i = threadIdx.x; i < NR * NSTRIP; i += 1024) {
        unsigned c = hist[i];
        if (c) atomicAdd(&counts[b * (NR * NSTRIP) + i], c);
    }
}

// exclusive prefix over both halves' bins; writes starts (immutable, +sentinel)
// and cursors (mutable, consumed by fill reservations)
__global__ __launch_bounds__(1024) void cm_prefix(
    const unsigned* __restrict__ counts,
    unsigned* __restrict__ starts0, unsigned* __restrict__ cursors0,
    unsigned* __restrict__ starts1, unsigned* __restrict__ cursors1)
{
    __shared__ unsigned sa[1024];
    int tid = threadIdx.x;

    // ---- half 0: 768 bins, bin k = (b*6+rl)*64+s, r = rl ----
    unsigned v = 0;
    if (tid < NBIN0) {
        int b = tid / (NRH0 * NSTRIP);
        int rl = (tid / NSTRIP) % NRH0;
        int s = tid & (NSTRIP - 1);
        v = counts[b * (NR * NSTRIP) + rl * NSTRIP + s];
    }
    sa[tid] = v;
    __syncthreads();
    for (int off = 1; off < 1024; off <<= 1) {
        unsigned x = sa[tid];
        if (tid >= off) x += sa[tid - off];
        __syncthreads();
        sa[tid] = x;
        __syncthreads();
    }
    if (tid < NBIN0) {
        unsigned ex = tid ? sa[tid - 1] : 0u;
        starts0[tid] = ex;
        cursors0[tid] = ex;
    }
    if (tid == 0) starts0[NBIN0] = sa[NBIN0 - 1];
    __syncthreads();

    // ---- half 1: 640 bins, bin k = (b*5+rl)*64+s, r = 6+rl ----
    v = 0;
    if (tid < NBIN1) {
        int b = tid / (NRH1 * NSTRIP);
        int rl = (tid / NSTRIP) % NRH1;
        int s = tid & (NSTRIP - 1);
        v = counts[b * (NR * NSTRIP) + (NRH0 + rl) * NSTRIP + s];
    }
    sa[tid] = v;
    __syncthreads();
    for (int off = 1; off < 1024; off <<= 1) {
        unsigned x = sa[tid];
        if (tid >= off) x += sa[tid - off];
        __syncthreads();
        sa[tid] = x;
        __syncthreads();
    }
    if (tid < NBIN1) {
        unsigned ex = tid ? sa[tid - 1] : 0u;
        starts1[tid] = ex;
        cursors1[tid] = ex;
    }
    if (tid == 0) starts1[NBIN1] = sa[NBIN1 - 1];
}

__global__ __launch_bounds__(256) void cm_fill(
    const float4* __restrict__ rec,
    unsigned* __restrict__ bins,
    unsigned* __restrict__ cursors,
    int nrh, int rbase)
{
    __shared__ unsigned char stash[FILL_E * NRH0];    // 12 KB worst case
    __shared__ unsigned cnt[NRH0 * NSTRIP];           // 384
    __shared__ unsigned base[NRH0 * NSTRIP];

    int b = blockIdx.x >> 7;                          // 128 blocks per batch
    int blk = blockIdx.x & 127;
    int ebase = blk * FILL_E;
    const float4* rb = rec + (size_t)b * NN;
    int nbin = nrh * NSTRIP;

    for (int i = threadIdx.x; i < nbin; i += 256) cnt[i] = 0u;
    __syncthreads();

    for (int k = 0; k < FILL_E / 256; ++k) {
        int el = k * 256 + threadIdx.x;
        float4 e4 = rb[ebase + el];
        for (int rl = 0; rl < nrh; ++rl) {
            unsigned sb = strip_of(e4.x, e4.y, e4.z, e4.w, (float)(rbase + rl));
            stash[el * nrh + rl] = (unsigned char)sb;
            if (sb & 0x80u) atomicAdd(&cnt[rl * NSTRIP + (int)(sb & 63u)], 1u);
        }
    }
    __syncthreads();
    for (int i = threadIdx.x; i < nbin; i += 256) {
        unsigned c = cnt[i];
        base[i] = c ? atomicAdd(&cursors[b * nbin + i], c) : 0u;
    }
    __syncthreads();
    for (int i = threadIdx.x; i < nbin; i += 256) cnt[i] = 0u;  // reuse as ranks
    __syncthreads();
    for (int k = 0; k < FILL_E / 256; ++k) {
        int el = k * 256 + threadIdx.x;
        for (int rl = 0; rl < nrh; ++rl) {
            unsigned sb = stash[el * nrh + rl];
            if (sb & 0x80u) {
                int bin = rl * NSTRIP + (int)(sb & 63u);
                unsigned rank = atomicAdd(&cnt[bin], 1u);
                unsigned entry = (unsigned)(ebase + el) | ((sb & 0x40u) << 12); // bit18
                bins[base[bin] + rank] = entry;
            }
        }
    }
}

__global__ __launch_bounds__(512) void cm_scan(
    const float4* __restrict__ rec,
    const float* __restrict__ tsq,
    const unsigned* __restrict__ bins,
    const unsigned* __restrict__ starts,
    int nrh, int rbase,
    float* __restrict__ accum)
{
    __shared__ float acc[4 * PLANE];   // 16 KB: [pol][iwe|iwt][4*256]

    int blk = blockIdx.x;
    int b  = blk / (nrh * NSTRIP);
    int rm = blk - b * (nrh * NSTRIP);
    int rl = rm >> 6;
    int s  = rm & 63;
    int r  = rbase + rl;
    int ty0 = s * SROWS;

    for (int i = threadIdx.x; i < 4 * PLANE; i += 512) acc[i] = 0.0f;
    __syncthreads();

    const float rf = (float)r;
    const float4* rb = rec + (size_t)b * NN;
    const float*  tb = tsq + (size_t)b * NN;

    auto process = [&](unsigned idx) {
        float4 ea = rb[idx];
        float rawts = tb[idx];
        int pi2 = (int)((unsigned)__float_as_int(rawts) >> 31);
        float tsv = fabsf(rawts);
        float wx = fmaf(rf, ea.z, ea.x);
        float wy = fmaf(rf, ea.w, ea.y);
        float fwx = floorf(wx);
        float fwy = floorf(wy);
        int xi = (int)fwx;
        int yi = (int)fwy;
        float axf = wx - fwx;
        float ayf = wy - fwy;
        float* ap = acc + pi2 * (2 * PLANE);
        float c00 = (1.0f - axf) * (1.0f - ayf);
        float c01 = axf * (1.0f - ayf);
        float c10 = (1.0f - axf) * ayf;
        float c11 = axf * ayf;
        #define CM_CORNER(XI, YI, WV)                                          \
            if ((XI) >= 0 && (XI) < WW && (YI) >= ty0 && (YI) < ty0 + SROWS) { \
                int liq = ((YI) - ty0) * WW + (XI);                            \
                atomicAdd(ap + liq,         (WV));                             \
                atomicAdd(ap + PLANE + liq, (WV) * tsv);                       \
            }
        CM_CORNER(xi,     yi,     c00)
        CM_CORNER(xi + 1, yi,     c01)
        CM_CORNER(xi,     yi + 1, c10)
        CM_CORNER(xi + 1, yi + 1, c11)
        #undef CM_CORNER
    };

    unsigned own_s = starts[blk], own_e = starts[blk + 1];
    for (unsigned i = own_s + threadIdx.x; i < own_e; i += 512)
        process(bins[i] & 0x3FFFFu);

    if (s > 0) {   // straddlers from strip s-1 land their yi+1 row here
        unsigned nb_s = starts[blk - 1];
        for (unsigned i = nb_s + threadIdx.x; i < own_s; i += 512) {
            unsigned ent = bins[i];
            if (ent >> 18) process(ent & 0x3FFFFu);
        }
    }
    __syncthreads();

    float ss = 0.0f, ins = 0.0f;
    for (int i = threadIdx.x; i < PLANE; i += 512) {
        float e0 = acc[i];
        float t0 = acc[PLANE + i];
        float e1 = acc[2 * PLANE + i];
        float t1 = acc[3 * PLANE + i];
        float a0 = t0 / (e0 + EPSF);
        float a1 = t1 / (e1 + EPSF);
        ss += a0 * a0 + a1 * a1;
        ins += ((e0 + e1) > 0.0f) ? 1.0f : 0.0f;
    }
    #pragma unroll
    for (int off = 32; off > 0; off >>= 1) {
        ss  += __shfl_down(ss, off, 64);
        ins += __shfl_down(ins, off, 64);
    }
    __syncthreads();
    int lane = threadIdx.x & 63;
    int wv = threadIdx.x >> 6;
    if (lane == 0) { acc[2 * wv] = ss; acc[2 * wv + 1] = ins; }
    __syncthreads();
    if (threadIdx.x == 0) {
        float tss = 0.0f, tin = 0.0f;
        #pragma unroll
        for (int w = 0; w < 8; ++w) { tss += acc[2 * w]; tin += acc[2 * w + 1]; }
        int br = b * NR + r;
        atomicAdd(&accum[br * 2],     tss);
        atomicAdd(&accum[br * 2 + 1], tin);
    }
}

__global__ void cm_final(const float* __restrict__ accum, float* __restrict__ out)
{
    int i = threadIdx.x;
    if (i < NB * NR) {
        out[i] = accum[i * 2] / (accum[i * 2 + 1] + EPSF);
    }
}

extern "C" void kernel_launch(void* const* d_in, const int* in_sizes, int n_in,
                              void* d_out, int out_size, void* d_ws, size_t ws_size,
                              hipStream_t stream) {
    const float* events = (const float*)d_in[0];
    const float* flow   = (const float*)d_in[1];

    char* ws = (char*)d_ws;
    size_t off = 0;
    float4* rec = (float4*)(ws + off);       off += (size_t)NB * NN * sizeof(float4);   // 8,388,608
    float* tsq = (float*)(ws + off);         off += (size_t)NB * NN * sizeof(float);    // 2,097,152
    unsigned* bins = (unsigned*)(ws + off);  off += (size_t)NB * NN * NRH0 * 4;         // 12,582,912
    unsigned* counts = (unsigned*)(ws + off); off += NB * NR * NSTRIP * 4;              // 5,632
    float* accum = (float*)(ws + off);       off += 256;                                // contiguous w/ counts
    unsigned* starts0 = (unsigned*)(ws + off);  off += (NBIN0 + 1) * 4 + 60;  off &= ~63ull;
    unsigned* cursors0 = (unsigned*)(ws + off); off += NBIN0 * 4 + 60;        off &= ~63ull;
    unsigned* starts1 = (unsigned*)(ws + off);  off += (NBIN1 + 1) * 4 + 60;  off &= ~63ull;
    unsigned* cursors1 = (unsigned*)(ws + off); off += NBIN1 * 4;

    // zero counts + accum (contiguous 5,888 B)
    hipMemsetAsync(counts, 0, NB * NR * NSTRIP * 4 + 256, stream);

    cm_prep<<<NB * NN / 1024, 1024, 0, stream>>>(events, flow, rec, tsq, counts);

    cm_prefix<<<1, 1024, 0, stream>>>(counts, starts0, cursors0, starts1, cursors1);

    cm_fill<<<NB * (NN / FILL_E), 256, 0, stream>>>(rec, bins, cursors0, NRH0, 0);
    cm_scan<<<NBIN0, 512, 0, stream>>>(rec, tsq, bins, starts0, NRH0, 0, accum);

    cm_fill<<<NB * (NN / FILL_E), 256, 0, stream>>>(rec, bins, cursors1, NRH1, NRH0);
    cm_scan<<<NBIN1, 512, 0, stream>>>(rec, tsq, bins, starts1, NRH1, NRH0, accum);

    cm_final<<<1, 64, 0, stream>>>(accum, (float*)d_out);
}